// Round 6
// baseline (1099.647 us; speedup 1.0000x reference)
//
#include <hip/hip_runtime.h>
#include <hip/hip_cooperative_groups.h>

#define N_NODES 100000
#define N_EDGES 200000
#define IN_FEATS 1024
#define H_FEATS 512
#define N_HEADS 4
#define HEAD_DIM 128
#define N_CLASSES 2983
#define BATCH 1024
#define NCHUNK2 782   // ceil(2*N_NODES / 256)

typedef __attribute__((ext_vector_type(8))) short short8;
typedef __attribute__((ext_vector_type(4))) float floatx4;

typedef __attribute__((address_space(1))) void global_as_void;
typedef __attribute__((address_space(3))) void lds_as_void;

__device__ __forceinline__ float bf2f(unsigned short u) {
    union { unsigned int i; float f; } x; x.i = ((unsigned int)u) << 16; return x.f;
}
__device__ __forceinline__ unsigned short f2bf(float f) {
    union { float f; unsigned int i; } x; x.f = f;
    unsigned int r = x.i + 0x7FFFu + ((x.i >> 16) & 1u);
    return (unsigned short)(r >> 16);
}
__device__ __forceinline__ void load_lds16(const void* g, void* l) {
    __builtin_amdgcn_global_load_lds((const global_as_void*)g, (lds_as_void*)l, 16, 0, 0);
}

// ---------------- GEMM ----------------
// C[M,N] = A @ BT^T.  A: bf16 (a_fp32=0) or fp32 (a_fp32=1).
// BK=64: two 32-col panels per barrier pair (halves barrier count vs BK=32;
// 8 global_load_lds in flight per drain).  K must be a multiple of 64.
// Row indirection: countp = device row count (null -> M); rowlist maps
// compact row -> node id.  a_dense=1: A stored compact (dense index);
// C stores + att logit stores scatter via rowlist.  a_dense=0: A via rowlist.
// XCD swizzle (n_tiles==8): mt = (bid&7) + 8*(bid>>6), nt = (bid>>3)&7.
// att epilogue: head h = nt; h<4 -> att_s/att_d, h>=4 -> att_s2/att_d2.
// Wave-halves summed in LDS (attbuf), ONE plain store per (node,h).
// LDS swizzle: 16B slot c of row r holds global k-chunk c ^ ((r>>1)&3).
__global__ __launch_bounds__(256, 3)
void gemm_kernel(const void* __restrict__ Ain, int a_fp32, int a_dense,
                 const unsigned short* __restrict__ BT,
                 void* __restrict__ Cout, const float* __restrict__ bias,
                 const float* __restrict__ att_s, const float* __restrict__ att_d,
                 const float* __restrict__ att_s2, const float* __restrict__ att_d2,
                 float* __restrict__ asrc, float* __restrict__ adst,
                 const int* __restrict__ rowlist, const int* __restrict__ countp,
                 int M, int N, int n_tiles, int K, int out_bf16)
{
    __shared__ __attribute__((aligned(16))) unsigned short As[2][128 * 32];
    __shared__ __attribute__((aligned(16))) unsigned short Bs[2][128 * 32];
    __shared__ float attbuf[128][4];   // [row][{ss,sd} x {half0,half1}]
    const int tid  = threadIdx.x;
    const int lane = tid & 63;
    const int wave = tid >> 6;
    const int bid = blockIdx.x;
    int mt, nt;
    if (n_tiles == 8) {
        mt = (bid & 7) + ((bid >> 6) << 3);
        nt = (bid >> 3) & 7;
    } else {
        mt = bid / n_tiles;
        nt = bid - mt * n_tiles;
    }
    const int m0 = mt * 128;
    const int n0 = nt * 128;
    int Mv = M;
    if (countp) Mv = countp[0];
    if (m0 >= Mv) return;           // uniform across block: safe before barriers
    const int wr = (wave >> 1) * 64;
    const int wc = (wave & 1) * 64;
    const int lm = lane & 15;
    const int quad = lane >> 4;

    auto arow = [&](int r) -> int {
        int gr = m0 + r; if (gr > Mv - 1) gr = Mv - 1;
        if (rowlist && !a_dense) gr = rowlist[gr];
        return gr;
    };

    // ---- hoisted staging addresses (invariant over K) ----
    const float* a_fp[2];
    const unsigned short* a_bf[2];
    char* a_lds[2];
    const unsigned short* b_bf[2];
    char* b_lds[2];
    if (a_fp32) {
        int row = tid >> 2, slot = tid & 3;
#pragma unroll
        for (int p = 0; p < 2; p++) {
            int r = p * 64 + row;
            a_fp[p] = (const float*)Ain + (size_t)arow(r) * K + (slot ^ ((r >> 1) & 3)) * 8;
        }
    } else {
#pragma unroll
        for (int i = 0; i < 2; i++) {
            int r = wave * 32 + i * 16 + (lane >> 2);
            a_bf[i] = (const unsigned short*)Ain + (size_t)arow(r) * K
                    + ((lane & 3) ^ ((r >> 1) & 3)) * 8;
            a_lds[i] = (char*)&As[0][0] + (size_t)(wave * 2 + i) * 1024;
        }
    }
#pragma unroll
    for (int i = 0; i < 2; i++) {
        int r = wave * 32 + i * 16 + (lane >> 2);
        int gn = n0 + r; if (gn > N - 1) gn = N - 1;
        b_bf[i] = BT + (size_t)gn * K + ((lane & 3) ^ ((r >> 1) & 3)) * 8;
        b_lds[i] = (char*)&Bs[0][0] + (size_t)(wave * 2 + i) * 1024;
    }

    floatx4 acc[4][4];
#pragma unroll
    for (int i = 0; i < 4; i++)
#pragma unroll
        for (int j = 0; j < 4; j++) acc[i][j] = (floatx4)0.0f;

    for (int k0 = 0; k0 < K; k0 += 64) {
        __syncthreads();
        if (a_fp32) {
            int row = tid >> 2, slot = tid & 3;
#pragma unroll
            for (int pp = 0; pp < 2; pp++)
#pragma unroll
            for (int p = 0; p < 2; p++) {
                int r = p * 64 + row;
                const float* ap = a_fp[p] + k0 + pp * 32;
                floatx4 f0 = *(const floatx4*)ap;
                floatx4 f1 = *(const floatx4*)(ap + 4);
                short8 v;
                v[0] = (short)f2bf(f0[0]); v[1] = (short)f2bf(f0[1]);
                v[2] = (short)f2bf(f0[2]); v[3] = (short)f2bf(f0[3]);
                v[4] = (short)f2bf(f1[0]); v[5] = (short)f2bf(f1[1]);
                v[6] = (short)f2bf(f1[2]); v[7] = (short)f2bf(f1[3]);
                *(short8*)&As[pp][r * 32 + slot * 8] = v;
            }
        } else {
#pragma unroll
            for (int pp = 0; pp < 2; pp++)
#pragma unroll
            for (int i = 0; i < 2; i++)
                load_lds16(a_bf[i] + k0 + pp * 32, a_lds[i] + pp * 8192);
        }
#pragma unroll
        for (int pp = 0; pp < 2; pp++)
#pragma unroll
        for (int i = 0; i < 2; i++)
            load_lds16(b_bf[i] + k0 + pp * 32, b_lds[i] + pp * 8192);
        __syncthreads();
#pragma unroll
        for (int pp = 0; pp < 2; pp++) {
            short8 af[4], bfr[4];
#pragma unroll
            for (int i = 0; i < 4; i++) {
                int ra = wr + i * 16 + lm;
                af[i] = *(const short8*)&As[pp][ra * 32 + ((quad ^ ((ra >> 1) & 3)) << 3)];
                int rb = wc + i * 16 + lm;
                bfr[i] = *(const short8*)&Bs[pp][rb * 32 + ((quad ^ ((rb >> 1) & 3)) << 3)];
            }
#pragma unroll
            for (int i = 0; i < 4; i++)
#pragma unroll
                for (int j = 0; j < 4; j++)
                    acc[i][j] = __builtin_amdgcn_mfma_f32_16x16x32_bf16(af[i], bfr[j], acc[i][j], 0, 0, 0);
        }
    }

    // fused attention logits (this block covers exactly one head's 128 cols;
    // each wave holds half the cols -> combine the two halves via LDS).
    if (att_s) {
        const int h = nt;
        const float* wsp = (h < 4) ? att_s : att_s2;
        const float* wdp = (h < 4) ? att_d : att_d2;
        const int hh = h & 3;
        const int half2 = (wc >> 6) * 2;   // 0 or 2
#pragma unroll
        for (int i = 0; i < 4; i++) {
#pragma unroll
            for (int r = 0; r < 4; r++) {
                float ss = 0.f, sd = 0.f;
#pragma unroll
                for (int j = 0; j < 4; j++) {
                    int c = wc + j * 16 + lm;
                    ss += acc[i][j][r] * wsp[hh * HEAD_DIM + c];
                    sd += acc[i][j][r] * wdp[hh * HEAD_DIM + c];
                }
#pragma unroll
                for (int off = 1; off < 16; off <<= 1) {
                    ss += __shfl_xor(ss, off);
                    sd += __shfl_xor(sd, off);
                }
                if (lm == 0) {
                    int rl = wr + i * 16 + quad * 4 + r;
                    attbuf[rl][half2]     = ss;
                    attbuf[rl][half2 + 1] = sd;
                }
            }
        }
        __syncthreads();
        if (tid < 128) {
            int grl = m0 + tid;
            if (grl < Mv) {
                int gr = rowlist ? rowlist[grl] : grl;
                asrc[(size_t)gr * 8 + h] = attbuf[tid][0] + attbuf[tid][2];
                adst[(size_t)gr * 8 + h] = attbuf[tid][1] + attbuf[tid][3];
            }
        }
    }

    // C store: C/D layout col=lane&15, row=quad*4+reg
#pragma unroll
    for (int i = 0; i < 4; i++) {
        int grb = wr + i * 16 + quad * 4;
#pragma unroll
        for (int j = 0; j < 4; j++) {
            int gc = n0 + wc + j * 16 + lm;
            if (gc < N) {
#pragma unroll
                for (int r = 0; r < 4; r++) {
                    int grl = m0 + grb + r;
                    if (grl < Mv) {
                        int gr = rowlist ? rowlist[grl] : grl;
                        float v = acc[i][j][r];
                        if (out_bf16) {
                            ((unsigned short*)Cout)[(size_t)gr * N + gc] = f2bf(v);
                        } else {
                            float b = bias ? bias[gc] : 0.0f;
                            ((float*)Cout)[(size_t)gr * N + gc] = v + b;
                        }
                    }
                }
            }
        }
    }
}

// ---------------- cooperative preprocessing mega-kernel ----------------
// Phases (grid.sync between): P0 zero cnt2+flagbuf; P1 weight transposes +
// mark1 + hist2; P2 mark0; P3 per-chunk scans (flagbuf->partialF/chunkF,
// cnt2->partialC/chunkC); P4 block0 scans chunk arrays; P5 finalize (lists,
// counts, rowptrc, cursor); P6 CSR fill + compact-row x->bf16 convert.
struct PrepArgs {
    const float *w0a, *w0b, *w1a, *w1b, *linw;
    unsigned short *WT0, *WT1, *WTl;
    const int *e1s, *e1d, *e2s, *e2d;
    int *flagbuf, *cnt2;
    int *partialF, *chunkF, *partialC, *chunkC;
    int *list1, *list0, *count1, *count0;
    int *rowptrc, *srcsc;
    const float* x;
    unsigned short* xc;
};

__global__ __launch_bounds__(256, 2)
void prep_all_kernel(PrepArgs a)
{
    cooperative_groups::grid_group g = cooperative_groups::this_grid();
    const int gsz = gridDim.x * 256;
    const int gid = blockIdx.x * 256 + threadIdx.x;
    const int t = threadIdx.x;
    __shared__ int sm[1024];
    __shared__ int ts[256];

    // P0: zero cnt2(2N) + flagbuf(2N)  (adjacent carves -> one linear sweep)
    for (int i = gid; i < 4 * N_NODES; i += gsz) a.cnt2[i] = 0;
    g.sync();

    // P1: transposes + mark1 + hist2
    for (int i = gid; i < 1024 * 1024; i += gsz) {
        int n = i >> 10, k = i & 1023;
        const float* W = (n < 512) ? a.w0a : a.w0b;
        a.WT0[i] = f2bf(W[(size_t)k * 512 + (n & 511)]);
    }
    for (int i = gid; i < 1024 * 512; i += gsz) {
        int n = i >> 9, k = i & 511;
        const float* W = (n < 512) ? a.w1a : a.w1b;
        a.WT1[i] = f2bf(W[(size_t)k * 512 + (n & 511)]);
    }
    for (int i = gid; i < N_CLASSES * 512; i += gsz) {
        int n = i >> 9, k = i & 511;
        a.WTl[i] = f2bf(a.linw[(size_t)k * N_CLASSES + n]);
    }
    for (int e = gid; e < N_EDGES; e += gsz) {
        if (e < BATCH) a.flagbuf[e] = 1;
        int d1 = a.e1d[e], d2 = a.e2d[e];
        if (d1 < BATCH) a.flagbuf[a.e1s[e]] = 1;
        if (d2 < BATCH) a.flagbuf[a.e2s[e]] = 1;
        atomicAdd(&a.cnt2[d1], 1);
        atomicAdd(&a.cnt2[N_NODES + d2], 1);
    }
    g.sync();

    // P2: mark0 (F0 = srcs of edges into F1, plus F1 itself)
    for (int e = gid; e < N_EDGES; e += gsz) {
        if (a.flagbuf[a.e1d[e]]) a.flagbuf[N_NODES + a.e1s[e]] = 1;
        if (a.flagbuf[a.e2d[e]]) a.flagbuf[N_NODES + a.e2s[e]] = 1;
    }
    for (int i = gid; i < N_NODES; i += gsz)
        if (a.flagbuf[i]) a.flagbuf[N_NODES + i] = 1;
    g.sync();

    // P3: per-chunk scans of flagbuf(2N) and cnt2(2N)
    for (int c = blockIdx.x; c < 2 * NCHUNK2; c += gridDim.x) {
        const int* src; int* pdst; int* cdst; int cb;
        if (c < NCHUNK2) { src = a.flagbuf; pdst = a.partialF; cdst = a.chunkF; cb = c; }
        else             { src = a.cnt2;    pdst = a.partialC; cdst = a.chunkC; cb = c - NCHUNK2; }
        int i = cb * 256 + t;
        int v = (i < 2 * N_NODES) ? src[i] : 0;
        sm[t] = v; __syncthreads();
        int val = v;
#pragma unroll
        for (int off = 1; off < 256; off <<= 1) {
            int u = (t >= off) ? sm[t - off] : 0;
            __syncthreads();
            val += u; sm[t] = val;
            __syncthreads();
        }
        if (i < 2 * N_NODES) pdst[i] = val - v;
        if (t == 255) cdst[cb] = val;
        __syncthreads();
    }
    g.sync();

    // P4: block 0 exclusive-scans chunkF then chunkC in place (n = NCHUNK2)
    if (blockIdx.x == 0) {
        for (int pass = 0; pass < 2; pass++) {
            int* c = pass ? a.chunkC : a.chunkF;
            for (int i = t; i < 1024; i += 256) sm[i] = (i < NCHUNK2) ? c[i] : 0;
            __syncthreads();
            int b4 = t * 4;
            int a0 = sm[b4], a1 = sm[b4 + 1], a2 = sm[b4 + 2], a3 = sm[b4 + 3];
            int s1 = a0, s2 = s1 + a1, s3 = s2 + a2, tot = s3 + a3;
            ts[t] = tot; __syncthreads();
            int val = tot;
#pragma unroll
            for (int off = 1; off < 256; off <<= 1) {
                int u = (t >= off) ? ts[t - off] : 0;
                __syncthreads();
                val += u; ts[t] = val;
                __syncthreads();
            }
            int exc = val - tot;
            sm[b4] = exc; sm[b4 + 1] = exc + s1; sm[b4 + 2] = exc + s2; sm[b4 + 3] = exc + s3;
            __syncthreads();
            for (int i = t; i < NCHUNK2; i += 256) c[i] = sm[i];
            __syncthreads();
        }
    }
    g.sync();

    // P5: finalize (lists/counts + rowptr/cursor)
    for (int i = gid; i < 2 * N_NODES; i += gsz) {
        int r = a.partialC[i] + a.chunkC[i >> 8];
        a.rowptrc[i] = r;
        a.cnt2[i] = r;                       // cursor
        if (i == 0) a.rowptrc[2 * N_NODES] = 2 * N_EDGES;
        int total1 = a.partialF[N_NODES] + a.chunkF[N_NODES >> 8];
        int pos = a.partialF[i] + a.chunkF[i >> 8];
        int f = a.flagbuf[i];
        if (i < N_NODES) {
            if (f) a.list1[pos] = i;
            if (i == 0) a.count1[0] = total1;
        } else {
            if (f) a.list0[pos - total1] = i - N_NODES;
            if (i == 2 * N_NODES - 1) a.count0[0] = pos + f - total1;
        }
    }
    g.sync();

    // P6: CSR fill + compact x->bf16 convert
    for (int e = gid; e < N_EDGES; e += gsz) {
        int p = atomicAdd(&a.cnt2[a.e1d[e]], 1);
        a.srcsc[p] = a.e1s[e];
        int q = atomicAdd(&a.cnt2[N_NODES + a.e2d[e]], 1);
        a.srcsc[q] = a.e2s[e];
    }
    int n0 = a.count0[0];
    int col = (t & 127) * 8;
    for (int i = blockIdx.x * 2 + (t >> 7); i < n0; i += gridDim.x * 2) {
        const floatx4* xp = (const floatx4*)(a.x + (size_t)a.list0[i] * IN_FEATS + col);
        floatx4 f0 = xp[0], f1 = xp[1];
        short8 v;
        v[0] = (short)f2bf(f0[0]); v[1] = (short)f2bf(f0[1]);
        v[2] = (short)f2bf(f0[2]); v[3] = (short)f2bf(f0[3]);
        v[4] = (short)f2bf(f1[0]); v[5] = (short)f2bf(f1[1]);
        v[6] = (short)f2bf(f1[2]); v[7] = (short)f2bf(f1[3]);
        *(short8*)(a.xc + (size_t)i * IN_FEATS + col) = v;
    }
}

// ---------------- fused dual-edge-type gather (grid-stride) ----------------
__global__ void gather2_kernel(const int* __restrict__ rowptrc, const int* __restrict__ srcsc,
                               const float* __restrict__ asrc, const float* __restrict__ adst,
                               const unsigned short* __restrict__ H,
                               const float* __restrict__ b1, const float* __restrict__ b2,
                               const int* __restrict__ dlist, const int* __restrict__ dcountp,
                               unsigned short* __restrict__ Out, int ndst, int do_lrelu)
{
    int nd = dcountp ? dcountp[0] : ndst;
    int lane = threadIdx.x & 63;
    int head = lane >> 4;      // 128 cols per head = 16 lanes * 8
    int col = lane * 8;
    for (int i = blockIdx.x * 4 + (threadIdx.x >> 6); i < nd; i += gridDim.x * 4) {
        int d = dlist ? dlist[i] : i;
        float r[8], acc[8];
        // ---- edge type 1: heads 0-3, H cols [0,512) ----
        {
            int beg = rowptrc[d], end = rowptrc[d + 1];
            float ad = adst[(size_t)d * 8 + head];
            float den = 0.f;
#pragma unroll
            for (int k = 0; k < 8; k++) acc[k] = 0.f;
            for (int j = beg; j < end; j++) {
                int s = srcsc[j];
                float v = asrc[(size_t)s * 8 + head] + ad;
                v = v > 0.f ? v : 0.2f * v;
                float ex = expf(v);
                den += ex;
                short8 hv = *(const short8*)(H + (size_t)s * 1024 + col);
#pragma unroll
                for (int k = 0; k < 8; k++) acc[k] += ex * bf2f((unsigned short)hv[k]);
            }
            float inv = den > 0.f ? 1.f / den : 0.f;
#pragma unroll
            for (int k = 0; k < 8; k++) r[k] = acc[k] * inv;
        }
        // ---- edge type 2: heads 4-7, H cols [512,1024) ----
        {
            int beg = rowptrc[N_NODES + d], end = rowptrc[N_NODES + d + 1];
            float ad = adst[(size_t)d * 8 + 4 + head];
            float den = 0.f;
#pragma unroll
            for (int k = 0; k < 8; k++) acc[k] = 0.f;
            for (int j = beg; j < end; j++) {
                int s = srcsc[j];
                float v = asrc[(size_t)s * 8 + 4 + head] + ad;
                v = v > 0.f ? v : 0.2f * v;
                float ex = expf(v);
                den += ex;
                short8 hv = *(const short8*)(H + (size_t)s * 1024 + 512 + col);
#pragma unroll
                for (int k = 0; k < 8; k++) acc[k] += ex * bf2f((unsigned short)hv[k]);
            }
            float inv = den > 0.f ? 1.f / den : 0.f;
#pragma unroll
            for (int k = 0; k < 8; k++) r[k] += acc[k] * inv;
        }
        short8 o;
#pragma unroll
        for (int k = 0; k < 8; k++) {
            float f = r[k] + b1[col + k] + b2[col + k];
            if (do_lrelu) f = f > 0.f ? f : 0.01f * f;
            o[k] = (short)f2bf(f);
        }
        *(short8*)(Out + (size_t)i * 512 + col) = o;
    }
}

extern "C" void kernel_launch(void* const* d_in, const int* in_sizes, int n_in,
                              void* d_out, int out_size, void* d_ws, size_t ws_size,
                              hipStream_t stream)
{
    const float* x    = (const float*)d_in[0];
    const int* e1s    = (const int*)d_in[1];
    const int* e1d    = (const int*)d_in[2];
    const int* e2s    = (const int*)d_in[3];
    const int* e2d    = (const int*)d_in[4];
    const float* w0a  = (const float*)d_in[6];
    const float* as0a = (const float*)d_in[7];
    const float* ad0a = (const float*)d_in[8];
    const float* b0a  = (const float*)d_in[9];
    const float* w0b  = (const float*)d_in[10];
    const float* as0b = (const float*)d_in[11];
    const float* ad0b = (const float*)d_in[12];
    const float* b0b  = (const float*)d_in[13];
    const float* w1a  = (const float*)d_in[14];
    const float* as1a = (const float*)d_in[15];
    const float* ad1a = (const float*)d_in[16];
    const float* b1a  = (const float*)d_in[17];
    const float* w1b  = (const float*)d_in[18];
    const float* as1b = (const float*)d_in[19];
    const float* ad1b = (const float*)d_in[20];
    const float* b1b  = (const float*)d_in[21];
    const float* linw = (const float*)d_in[22];
    const float* linb = (const float*)d_in[23];
    float* out = (float*)d_out;
    (void)in_sizes; (void)n_in; (void)out_size;

    char* ws = (char*)d_ws;
    size_t off = 0;
    auto carve = [&](size_t bytes) -> void* {
        void* p = ws + off; off += (bytes + 255) & ~(size_t)255; return p;
    };
    unsigned short* WT0 = (unsigned short*)carve((size_t)2 * H_FEATS * IN_FEATS * 2); // [1024][1024]
    unsigned short* WT1 = (unsigned short*)carve((size_t)2 * H_FEATS * H_FEATS * 2);  // [1024][512]
    unsigned short* WTl = (unsigned short*)carve((size_t)N_CLASSES * H_FEATS * 2);
    unsigned short* Hbf = (unsigned short*)carve((size_t)N_NODES * 1024 * 2);  // GEMM out, node-indexed
    unsigned short* H1c = (unsigned short*)carve((size_t)N_NODES * H_FEATS * 2); // F1-compact layer-0 out
    unsigned short* h2s = (unsigned short*)carve((size_t)BATCH * H_FEATS * 2);
    float* asrc = (float*)carve((size_t)N_NODES * 8 * 4);
    float* adst = (float*)carve((size_t)N_NODES * 8 * 4);
    // cnt2 and flagbuf adjacent (2N*4 = 800000 bytes, exactly 256-aligned)
    // so P0's single sweep zeroes both.
    int* cnt2    = (int*)carve((size_t)2 * N_NODES * 4);   // histogram, then cursor
    int* flagbuf = (int*)carve((size_t)2 * N_NODES * 4);   // [flag1 | flag0]
    int* rowptrc = (int*)carve((size_t)(2 * N_NODES + 1) * 4);
    int* srcsc   = (int*)carve((size_t)2 * N_EDGES * 4);
    int* partialF= (int*)carve((size_t)2 * N_NODES * 4);
    int* partialC= (int*)carve((size_t)2 * N_NODES * 4);
    int* chunkF  = (int*)carve((size_t)1024 * 4);
    int* chunkC  = (int*)carve((size_t)1024 * 4);
    int* list1   = (int*)carve((size_t)N_NODES * 4);
    int* list0   = (int*)carve((size_t)N_NODES * 4);
    int* count1  = (int*)carve(256);
    int* count0  = (int*)carve(256);
    // compact bf16 A for layer 0 (worst case all nodes): only if ws allows.
    // Decision depends only on ws_size -> identical every call (capture-safe).
    unsigned short* xc = nullptr;
    {
        size_t need = (size_t)N_NODES * IN_FEATS * 2;
        if (off + need <= ws_size) xc = (unsigned short*)carve(need);
    }

    const int MT8 = (((N_NODES + 127) / 128) + 7) & ~7;   // 784, multiple of 8 for swizzle

    // 1. cooperative preprocessing (memset + transposes + frontier + CSR + cvt)
    {
        PrepArgs pa;
        pa.w0a = w0a; pa.w0b = w0b; pa.w1a = w1a; pa.w1b = w1b; pa.linw = linw;
        pa.WT0 = WT0; pa.WT1 = WT1; pa.WTl = WTl;
        pa.e1s = e1s; pa.e1d = e1d; pa.e2s = e2s; pa.e2d = e2d;
        pa.flagbuf = flagbuf; pa.cnt2 = cnt2;
        pa.partialF = partialF; pa.chunkF = chunkF; pa.partialC = partialC; pa.chunkC = chunkC;
        pa.list1 = list1; pa.list0 = list0; pa.count1 = count1; pa.count0 = count0;
        pa.rowptrc = rowptrc; pa.srcsc = srcsc;
        pa.x = x; pa.xc = xc ? xc : (unsigned short*)Hbf;
        void* params[] = { &pa };
        hipLaunchCooperativeKernel((void*)prep_all_kernel, dim3(512), dim3(256),
                                   params, 0, stream);
    }

    // 2. layer 0: fused N=1024 GEMM over F0 rows
    if (xc) {
        gemm_kernel<<<MT8 * 8, 256, 0, stream>>>(xc, 0, 1, WT0, Hbf, nullptr,
                                                 as0a, ad0a, as0b, ad0b, asrc, adst,
                                                 list0, count0,
                                                 N_NODES, 1024, 8, IN_FEATS, 1);
    } else {
        gemm_kernel<<<MT8 * 8, 256, 0, stream>>>(x, 1, 0, WT0, Hbf, nullptr,
                                                 as0a, ad0a, as0b, ad0b, asrc, adst,
                                                 list0, count0,
                                                 N_NODES, 1024, 8, IN_FEATS, 1);
    }
    // 3. gather over F1 dsts -> H1c (compact)
    gather2_kernel<<<2048, 256, 0, stream>>>(rowptrc, srcsc, asrc, adst, Hbf, b0a, b0b,
                                             list1, count1, H1c, N_NODES, 1);
    // 4. layer 1: compact GEMM over F1 rows (scatter into Hbf)
    gemm_kernel<<<MT8 * 8, 256, 0, stream>>>(H1c, 0, 1, WT1, Hbf, nullptr,
                                             as1a, ad1a, as1b, ad1b, asrc, adst,
                                             list1, count1,
                                             N_NODES, 1024, 8, H_FEATS, 1);
    // 5. gather over BATCH dsts -> h2s
    gather2_kernel<<<256, 256, 0, stream>>>(rowptrc, srcsc, asrc, adst, Hbf, b1a, b1b,
                                            nullptr, nullptr, h2s, BATCH, 0);
    // 6. classification head
    const int HN_T = (N_CLASSES + 127) / 128;   // 24
    gemm_kernel<<<(BATCH / 128) * HN_T, 256, 0, stream>>>(h2s, 0, 0, WTl, out, linb,
                                                          nullptr, nullptr, nullptr, nullptr,
                                                          nullptr, nullptr, nullptr, nullptr,
                                                          BATCH, N_CLASSES, HN_T, H_FEATS, 0);
}